// Round 10
// baseline (198.302 us; speedup 1.0000x reference)
//
#include <hip/hip_runtime.h>
#include <cstdint>
#include <type_traits>

typedef __attribute__((ext_vector_type(8))) __bf16 bf16x8;
typedef __attribute__((ext_vector_type(4))) float f32x4;
using u16 = unsigned short;
using u32 = unsigned int;

#define D_MODEL 1024
#define N_HEADS 16
#define D_K     64
#define SEQ     2048
#define BATCH   2
#define NTOKENS (BATCH * SEQ)
#define SCALE   0.125f
#define LOG2E   1.44269504088896340736f
#define C2      (SCALE * LOG2E)

__device__ __forceinline__ u16 f32_to_bf16(float f) {
    union { float f; u32 u; } v; v.f = f;
    u32 r = (v.u + 0x7fffu + ((v.u >> 16) & 1u)) >> 16;
    return (u16)r;
}

// pack two f32 -> two bf16 (round-half-up): 3 VALU
__device__ __forceinline__ u32 pack_bf16_pair(float a, float b) {
    u32 ua = __builtin_bit_cast(u32, a) + 0x8000u;
    u32 ub = __builtin_bit_cast(u32, b) + 0x8000u;
    return __builtin_amdgcn_perm(ub, ua, 0x07060302);
}

// async global->LDS DMA, 16B/lane; LDS dst wave-uniform base + lane*16
typedef const __attribute__((address_space(1))) u32* gas_ptr;
typedef __attribute__((address_space(3))) u32* las_ptr;
__device__ __forceinline__ void gl2lds16(const u16* g, u16* l) {
    __builtin_amdgcn_global_load_lds((gas_ptr)g, (las_ptr)l, 16, 0, 0);
}

// ---------------- fp32 -> bf16 convert: x + 4 weights in ONE kernel ----------------
__global__ __launch_bounds__(256) void cvt_all(const float* __restrict__ x,
                                               const float* __restrict__ Wq, const float* __restrict__ Wk,
                                               const float* __restrict__ Wv, const float* __restrict__ Wo,
                                               u16* __restrict__ xb,
                                               u16* __restrict__ wq, u16* __restrict__ wk,
                                               u16* __restrict__ wv, u16* __restrict__ wo) {
    const int NX = NTOKENS * D_MODEL;          // 4 M
    size_t i = (size_t)(blockIdx.x * 256 + threadIdx.x) * 4;
    const float* src; u16* dst; size_t off;
    if (i < (size_t)NX) { src = x; dst = xb; off = i; }
    else {
        size_t j = i - NX;
        int w = (int)(j >> 20);
        off = j & ((1u << 20) - 1);
        src = (w == 0) ? Wq : (w == 1) ? Wk : (w == 2) ? Wv : Wo;
        dst = (w == 0) ? wq : (w == 1) ? wk : (w == 2) ? wv : wo;
    }
    float4 f = *(const float4*)(src + off);
    u32 lo = (u32)f32_to_bf16(f.x) | ((u32)f32_to_bf16(f.y) << 16);
    u32 hi = (u32)f32_to_bf16(f.z) | ((u32)f32_to_bf16(f.w) << 16);
    uint2 o; o.x = lo; o.y = hi;
    *(uint2*)(dst + off) = o;
}

// ---------------- Fused QKV projection GEMM (m97 structure, BK=32) ----------------
// Flat grid 768. f<512: Q/K  (C = x * W^T, rows = tokens).
//                f>=512: V^T (C = Wv * x^T, rows = features -> Vt row-major, coalesced).
// NOTE: BK=64 (32 KB LDS, 8 DMA/barrier) regressed to 69 us (occupancy 17%, MfmaUtil 14%)
// — the m132 trap. Keep BK=32 / 16 KB.
__global__ __launch_bounds__(256) void gemm_qkv(const u16* __restrict__ xb,
                                                const u16* __restrict__ wq,
                                                const u16* __restrict__ wk,
                                                const u16* __restrict__ wv,
                                                u16* __restrict__ Qb, u16* __restrict__ Kb,
                                                u16* __restrict__ Vt) {
    __shared__ __align__(16) u16 As[128 * 32];
    __shared__ __align__(16) u16 Bs[128 * 32];

    const int tid  = threadIdx.x;
    const int wave = tid >> 6, lane = tid & 63;
    const int quad = lane >> 4, l4 = lane & 15;
    const int wm = wave >> 1, wn = wave & 1;
    const int f = blockIdx.x;

    const u16 *Abase, *Bbase;
    if (f < 512) {
        const int m0 = (f & 31) * 128, t = f >> 5;
        Abase = xb + (size_t)m0 * D_MODEL;
        Bbase = ((t < 8) ? wq : wk) + (size_t)(t & 7) * 128 * D_MODEL;
    } else {
        const int g = f - 512;
        Abase = wv + (size_t)(g & 7) * 128 * D_MODEL;    // rows = features
        Bbase = xb + (size_t)(g >> 3) * 128 * D_MODEL;   // rows = tokens
    }

    f32x4 acc[4][4] = {};

    const int r0 = wave * 16 + (lane >> 2);
    const int ch = (lane & 3) * 8;
    const u16* Ag0 = Abase + (size_t)r0 * D_MODEL + ch;
    const u16* Bg0 = Bbase + (size_t)r0 * D_MODEL + ch;
    u16* AsW = As + wave * 512;
    u16* BsW = Bs + wave * 512;

    for (int kt = 0; kt < 32; ++kt) {
        const int ko = kt * 32;
        __syncthreads();
        gl2lds16(Ag0 + ko, AsW);
        gl2lds16(Ag0 + (size_t)64 * D_MODEL + ko, AsW + 2048);
        gl2lds16(Bg0 + ko, BsW);
        gl2lds16(Bg0 + (size_t)64 * D_MODEL + ko, BsW + 2048);
        __syncthreads();

        bf16x8 af[4], bfr[4];
#pragma unroll
        for (int mt = 0; mt < 4; mt++)
            af[mt] = *(const bf16x8*)&As[(wm * 64 + mt * 16 + l4) * 32 + quad * 8];
#pragma unroll
        for (int nt = 0; nt < 4; nt++)
            bfr[nt] = *(const bf16x8*)&Bs[(wn * 64 + nt * 16 + l4) * 32 + quad * 8];
#pragma unroll
        for (int mt = 0; mt < 4; mt++)
#pragma unroll
            for (int nt = 0; nt < 4; nt++)
                acc[mt][nt] = __builtin_amdgcn_mfma_f32_16x16x32_bf16(af[mt], bfr[nt], acc[mt][nt], 0, 0, 0);
    }

#pragma unroll
    for (int mt = 0; mt < 4; mt++)
#pragma unroll
        for (int nt = 0; nt < 4; nt++)
#pragma unroll
            for (int r = 0; r < 4; r++) {
                int mrow = wm * 64 + mt * 16 + quad * 4 + r;
                int ncol = wn * 64 + nt * 16 + l4;
                float v = acc[mt][nt][r];
                if (f < 512) {
                    const int m0 = (f & 31) * 128, t = f >> 5;
                    if (t < 8)
                        Qb[(size_t)(m0 + mrow) * D_MODEL + (t & 7) * 128 + ncol] = f32_to_bf16(v * C2);
                    else
                        Kb[(size_t)(m0 + mrow) * D_MODEL + (t & 7) * 128 + ncol] = f32_to_bf16(v);
                } else {
                    const int g = f - 512;
                    Vt[(size_t)((g & 7) * 128 + mrow) * NTOKENS + (g >> 3) * 128 + ncol] = f32_to_bf16(v);
                }
            }
}

// ---------------- Output projection GEMM: fp32 out, 64x128 tile, m97 staging ----------------
__global__ __launch_bounds__(256) void gemm_out(const u16* __restrict__ A,
                                                const u16* __restrict__ Bw,
                                                float* __restrict__ C) {
    __shared__ __align__(16) u16 As[64 * 32];
    __shared__ __align__(16) u16 Bs[128 * 32];

    const int tid  = threadIdx.x;
    const int wave = tid >> 6, lane = tid & 63;
    const int quad = lane >> 4, l4 = lane & 15;
    const int m0 = blockIdx.y * 64, n0 = blockIdx.x * 128;

    f32x4 acc[4][2] = {};

    const int r0 = wave * 16 + (lane >> 2);
    const int ch = (lane & 3) * 8;
    const u16* Ag0 = A  + (size_t)(m0 + r0) * D_MODEL + ch;
    const u16* Bg0 = Bw + (size_t)(n0 + r0) * D_MODEL + ch;
    u16* AsW = As + wave * 512;
    u16* BsW = Bs + wave * 512;

    for (int kt = 0; kt < 32; ++kt) {
        const int ko = kt * 32;
        __syncthreads();
        gl2lds16(Ag0 + ko, AsW);
        gl2lds16(Bg0 + ko, BsW);
        gl2lds16(Bg0 + (size_t)64 * D_MODEL + ko, BsW + 2048);
        __syncthreads();

        bf16x8 af[4], bfr[2];
#pragma unroll
        for (int mt = 0; mt < 4; mt++)
            af[mt] = *(const bf16x8*)&As[(mt * 16 + l4) * 32 + quad * 8];
#pragma unroll
        for (int nt = 0; nt < 2; nt++)
            bfr[nt] = *(const bf16x8*)&Bs[(wave * 32 + nt * 16 + l4) * 32 + quad * 8];
#pragma unroll
        for (int mt = 0; mt < 4; mt++)
#pragma unroll
            for (int nt = 0; nt < 2; nt++)
                acc[mt][nt] = __builtin_amdgcn_mfma_f32_16x16x32_bf16(af[mt], bfr[nt], acc[mt][nt], 0, 0, 0);
    }

#pragma unroll
    for (int mt = 0; mt < 4; mt++)
#pragma unroll
        for (int nt = 0; nt < 2; nt++)
#pragma unroll
            for (int r = 0; r < 4; r++) {
                int m = m0 + mt * 16 + quad * 4 + r;
                int n = n0 + wave * 32 + nt * 16 + l4;
                C[(size_t)m * D_MODEL + n] = acc[mt][nt][r];
            }
}

// ---------------- Flash attention: kv-split + permuted-V PV(K=32) + MFMA lsum ----------------
// Flat grid 512, 512 thr. bid -> h=(bid&7)|(((bid>>3)&1)<<3), b=(bid>>4)&1, qb=bid>>5.
// Block = 128 q rows; 8 waves = 4 qg x 2 kv (32 q x 32 keys each).
// V staged with within-tile key permutation kappa=16*n2+4*qk+r -> 8*qk+4*n2+r so the
// S^T C-layout registers form a K=32 A-fragment directly (PV uses 16x16x32, b128 V reads).
// V row 64 = ones => one extra PV MFMA per q-subtile computes the softmax denominator.
// Q pre-scaled by SCALE*LOG2E; no-max softmax (logits bounded by construction).
__global__ __launch_bounds__(512, 4) void attn(const u16* __restrict__ Q,
                                               const u16* __restrict__ K,
                                               const u16* __restrict__ Vt,
                                               u16* __restrict__ O) {
    // K buffers: 2 x 64 rows x 72 ; V buffers: 2 x 80 rows x 72 (rows 64..79: ones+zeros)
    __shared__ __align__(16) u16 smem[2 * 64 * 72 + 2 * 80 * 72];   // 41472 B
    u16* KsB = smem;
    u16* VsB = smem + 2 * 64 * 72;
    const int KBUF = 64 * 72, VBUF = 80 * 72;

    const int tid  = threadIdx.x;
    const int wave = tid >> 6, lane = tid & 63;
    const int quad = lane >> 4, l4 = lane & 15;
    const int qg = wave & 3, kv = wave >> 2;
    const int bid = blockIdx.x;
    const int h  = (bid & 7) | (((bid >> 3) & 1) << 3);
    const int b  = (bid >> 4) & 1;
    const int q0 = (bid >> 5) * 128;
    const size_t headoff = (size_t)b * SEQ * D_MODEL + (size_t)h * D_K;

    // init V rows 64..79 of both buffers: row 64 = 1.0 bf16, rows 65..79 = 0
    for (int i = tid; i < 2 * 16 * 72; i += 512) {
        int buf = i / (16 * 72), rem = i % (16 * 72);
        VsB[buf * VBUF + (64 + rem / 72) * 72 + (rem % 72)] = (rem / 72 == 0) ? (u16)0x3F80 : (u16)0;
    }

    // staging: threads 0-255 -> K, 256-511 -> V; 32 B per thread
    const int sarr = tid >> 8;
    const int st   = tid & 255;
    const int srow = st >> 2, sc = st & 3;
    const u16* gsrc = (sarr == 0)
        ? K  + headoff + (size_t)srow * D_MODEL + sc * 16
        : Vt + (size_t)(h * 64 + srow) * NTOKENS + (size_t)b * SEQ + sc * 16;
    const size_t gstep = (sarr == 0) ? (size_t)64 * D_MODEL : 64;
    u16* kw0 = KsB + srow * 72 + sc * 16;
    u16* vw0 = VsB + srow * 72 + (sc >> 1) * 32 + (sc & 1) * 4;   // permuted base; groups at +g*8

    // Q fragments straight from global (one-time): 2 q-subtiles x 2 k-halves
    bf16x8 qa[2][2];
#pragma unroll
    for (int qs = 0; qs < 2; qs++) {
        const u16* qp = Q + headoff + (size_t)(q0 + qg * 32 + qs * 16 + l4) * D_MODEL + quad * 8;
        qa[qs][0] = *(const bf16x8*)qp;
        qa[qs][1] = *(const bf16x8*)(qp + 32);
    }

    int4 pr0 = *(const int4*)gsrc;
    int4 pr1 = *(const int4*)(gsrc + 8);

    f32x4 acc_o[2][4] = {};
    f32x4 acc_l[2] = {};

    for (int it = 0; it < 32; ++it) {
        if (sarr == 0) {
            u16* d = kw0 + (it & 1) * KBUF;
            *(int4*)d       = pr0;
            *(int4*)(d + 8) = pr1;
        } else {
            u16* d = vw0 + (it & 1) * VBUF;
            const uint2* h0 = (const uint2*)&pr0;
            const uint2* h1 = (const uint2*)&pr1;
            *(uint2*)(d)      = h0[0];   // keys 4g+0..3 -> permuted slot g*8
            *(uint2*)(d + 8)  = h0[1];
            *(uint2*)(d + 16) = h1[0];
            *(uint2*)(d + 24) = h1[1];
        }
        __syncthreads();

        const u16* gn = gsrc + (size_t)((it + 1) & 31) * gstep;   // wraps: harmless reload
        pr0 = *(const int4*)gn;
        pr1 = *(const int4*)(gn + 8);

        const u16* ksr = KsB + (it & 1) * KBUF;
        const u16* vsr = VsB + (it & 1) * VBUF;

        // S^T = K Q^T for this wave's 32 keys (2 nt tiles) x 32 q (2 subtiles)
        f32x4 sacc[2][2] = {};
#pragma unroll
        for (int n2 = 0; n2 < 2; n2++) {
            const int krow = kv * 32 + n2 * 16 + l4;
            bf16x8 kb0 = *(const bf16x8*)&ksr[krow * 72 + quad * 8];
            bf16x8 kb1 = *(const bf16x8*)&ksr[krow * 72 + 32 + quad * 8];
#pragma unroll
            for (int qs = 0; qs < 2; qs++) {
                sacc[qs][n2] = __builtin_amdgcn_mfma_f32_16x16x32_bf16(kb0, qa[qs][0], sacc[qs][n2], 0, 0, 0);
                sacc[qs][n2] = __builtin_amdgcn_mfma_f32_16x16x32_bf16(kb1, qa[qs][1], sacc[qs][n2], 0, 0, 0);
            }
        }

        // p = exp2(s); lane holds keys kappa'=16n2+4quad+r -> packed as k=quad*8+n2*4+r:
        // a legal K=32 A-fragment over the permuted key order.
        union { u32 u[4]; bf16x8 v; } pp[2];
#pragma unroll
        for (int qs = 0; qs < 2; qs++)
#pragma unroll
            for (int n2 = 0; n2 < 2; n2++) {
                float p0 = __builtin_amdgcn_exp2f(sacc[qs][n2][0]);
                float p1 = __builtin_amdgcn_exp2f(sacc[qs][n2][1]);
                float p2 = __builtin_amdgcn_exp2f(sacc[qs][n2][2]);
                float p3 = __builtin_amdgcn_exp2f(sacc[qs][n2][3]);
                pp[qs].u[n2 * 2]     = pack_bf16_pair(p0, p1);
                pp[qs].u[n2 * 2 + 1] = pack_bf16_pair(p2, p3);
            }

        // O += P V (K=32 MFMA, permuted keys) ; denominator via ones-row
#pragma unroll
        for (int dvt = 0; dvt < 4; dvt++) {
            bf16x8 vfr = *(const bf16x8*)&vsr[(dvt * 16 + l4) * 72 + kv * 32 + quad * 8];
#pragma unroll
            for (int qs = 0; qs < 2; qs++)
                acc_o[qs][dvt] = __builtin_amdgcn_mfma_f32_16x16x32_bf16(pp[qs].v, vfr, acc_o[qs][dvt], 0, 0, 0);
        }
        {
            bf16x8 ofr = *(const bf16x8*)&vsr[(64 + l4) * 72 + kv * 32 + quad * 8];
#pragma unroll
            for (int qs = 0; qs < 2; qs++)
                acc_l[qs] = __builtin_amdgcn_mfma_f32_16x16x32_bf16(pp[qs].v, ofr, acc_l[qs], 0, 0, 0);
        }
    }
    // acc_l: lane (l4=0, quad) holds l[q = quad*4+r] in elem r (kv-partial)

    // combine kv partials through LDS overlay:
    // Of[128 q][64 dv] f32 = bytes [0, 32768) ; Lf[128] f32 = bytes [32768, 33280)
    float* Of = (float*)smem;
    float* Lf = (float*)(smem + 16384);        // u16-elem 16384 = byte 32768
    __syncthreads();   // all K/V reads done
    if (kv == 1) {
#pragma unroll
        for (int qs = 0; qs < 2; qs++) {
#pragma unroll
            for (int dvt = 0; dvt < 4; dvt++)
#pragma unroll
                for (int r = 0; r < 4; r++)
                    Of[(qg * 32 + qs * 16 + quad * 4 + r) * 64 + dvt * 16 + l4] = acc_o[qs][dvt][r];
            if (l4 == 0)
#pragma unroll
                for (int r = 0; r < 4; r++)
                    Lf[qg * 32 + qs * 16 + quad * 4 + r] = acc_l[qs][r];
        }
    }
    __syncthreads();
    if (kv == 0) {
#pragma unroll
        for (int qs = 0; qs < 2; qs++)
#pragma unroll
            for (int r = 0; r < 4; r++) {
                float lown = __shfl(acc_l[qs][r], quad * 16, 64);   // from lane (l4=0, same quad)
                float ltot = lown + Lf[qg * 32 + qs * 16 + quad * 4 + r];
                float linv = 1.f / ltot;
                int qrow = q0 + qg * 32 + qs * 16 + quad * 4 + r;
#pragma unroll
                for (int dvt = 0; dvt < 4; dvt++) {
                    float v = acc_o[qs][dvt][r] +
                              Of[(qg * 32 + qs * 16 + quad * 4 + r) * 64 + dvt * 16 + l4];
                    O[headoff + (size_t)qrow * D_MODEL + dvt * 16 + l4] = f32_to_bf16(v * linv);
                }
            }
    }
}

// ---------------- launch ----------------
extern "C" void kernel_launch(void* const* d_in, const int* in_sizes, int n_in,
                              void* d_out, int out_size, void* d_ws, size_t ws_size,
                              hipStream_t stream) {
    const float* x  = (const float*)d_in[0];
    const float* Wq = (const float*)d_in[1];
    const float* Wk = (const float*)d_in[2];
    const float* Wv = (const float*)d_in[3];
    const float* Wo = (const float*)d_in[4];

    const int NW = D_MODEL * D_MODEL;      // 1,048,576

    char* ws = (char*)d_ws;
    u16* xb = (u16*)ws;                    // 8 MB; reused as attn output O
    u16* wq = (u16*)(ws + (8u << 20));
    u16* wk = wq + NW;
    u16* wv = wk + NW;
    u16* wo = wv + NW;
    u16* Qb  = (u16*)(ws + (16u << 20));
    u16* Kb  = (u16*)(ws + (24u << 20));
    u16* Vtb = (u16*)(ws + (32u << 20));   // V^T: [1024 features][4096 tokens]

    cvt_all<<<8192, 256, 0, stream>>>(x, Wq, Wk, Wv, Wo, xb, wq, wk, wv, wo);

    gemm_qkv<<<768, 256, 0, stream>>>(xb, wq, wk, wv, Qb, Kb, Vtb);

    attn<<<512, 512, 0, stream>>>(Qb, Kb, Vtb, xb);

    gemm_out<<<dim3(8, 64), 256, 0, stream>>>(xb, wo, (float*)d_out);
}